// Round 2
// baseline (111.129 us; speedup 1.0000x reference)
//
#include <hip/hip_runtime.h>

#define NROWS 8192
#define HALF  4096
#define DIM   256
#define JS    16                 // j-splits across grid
#define JRANGE (NROWS / JS)      // 512 columns per block
#define JTILES (JRANGE / 16)     // 32 tiles of 16 j each
#define IPB   256                // i rows per block
#define IPW   64                 // i rows per wave

typedef short bf16x8 __attribute__((ext_vector_type(8)));
typedef float f32x4  __attribute__((ext_vector_type(4)));

__device__ __forceinline__ unsigned short f2bf(float f) {
    unsigned int u = __float_as_uint(f);
    u += 0x7FFFu + ((u >> 16) & 1u);          // round-to-nearest-even
    return (unsigned short)(u >> 16);
}

// ---------------- phase 0a: fp32 -> bf16 convert (z = [z1; z2]) ----------------
__global__ void k_conv(const float* __restrict__ z1, const float* __restrict__ z2,
                       unsigned short* __restrict__ zb) {
    int t = blockIdx.x * blockDim.x + threadIdx.x;   // 0 .. 262143
    int e = t * 8;                                    // flat element index
    const float* src = (e < HALF * DIM) ? (z1 + e) : (z2 + (e - HALF * DIM));
    float4 a = ((const float4*)src)[0];
    float4 b = ((const float4*)src)[1];
    unsigned int r0 = (unsigned int)f2bf(a.x) | ((unsigned int)f2bf(a.y) << 16);
    unsigned int r1 = (unsigned int)f2bf(a.z) | ((unsigned int)f2bf(a.w) << 16);
    unsigned int r2 = (unsigned int)f2bf(b.x) | ((unsigned int)f2bf(b.y) << 16);
    unsigned int r3 = (unsigned int)f2bf(b.z) | ((unsigned int)f2bf(b.w) << 16);
    uint4 v; v.x = r0; v.y = r1; v.z = r2; v.w = r3;
    ((uint4*)zb)[t] = v;
}

// ---------------- phase 0b: positive-pair dots in exact fp32 ----------------
__global__ void k_pos(const float* __restrict__ z1, const float* __restrict__ z2,
                      float* __restrict__ pos) {
    int w = threadIdx.x >> 6, lane = threadIdx.x & 63;
    int row = blockIdx.x * 4 + w;                    // 1024 blocks * 4 = 4096
    float4 a = *(const float4*)(z1 + row * DIM + lane * 4);
    float4 b = *(const float4*)(z2 + row * DIM + lane * 4);
    float d = a.x * b.x + a.y * b.y + a.z * b.z + a.w * b.w;
    #pragma unroll
    for (int k = 32; k; k >>= 1) d += __shfl_xor(d, k);
    if (lane == 0) pos[row] = 2.0f * d;              // sim units (1/T = 2)
}

// ---------------- main: MFMA matmul + online LSE ----------------
__global__ __launch_bounds__(256, 2)
void k_main(const unsigned short* __restrict__ zb, float2* __restrict__ part) {
    __shared__ __align__(16) char lds[2][8192];      // 2 x (16 j-rows x 512B)

    const int tid  = threadIdx.x;
    const int w    = tid >> 6;
    const int lane = tid & 63;
    const int col  = lane & 15;        // i-local (C column)
    const int kg   = lane >> 4;        // k-group / j-subrow group
    const int ib   = blockIdx.x & 31;  // 32 i-tiles
    const int js   = blockIdx.x >> 5;  // 16 j-splits
    const int iw   = ib * IPB + w * IPW;
    const int jb0  = js * JRANGE;

    // preload B fragments (i side): 4 subtiles x 8 k-steps, bf16x8 each
    bf16x8 bf[4][8];
    #pragma unroll
    for (int is = 0; is < 4; ++is) {
        const char* rowp = (const char*)zb + (size_t)(iw + is * 16 + col) * 512;
        #pragma unroll
        for (int kk = 0; kk < 8; ++kk)
            bf[is][kk] = *(const bf16x8*)(rowp + kk * 64 + kg * 16);
    }

    float m[4], l[4];
    #pragma unroll
    for (int is = 0; is < 4; ++is) { m[is] = -1e30f; l[is] = 0.0f; }

    const int swz   = (lane & 7) << 4;   // XOR swizzle key: (row&7)<<4, row = col
    const int rbase = col * 512;
    const int dr    = col - kg * 4;      // which acc reg hits the diagonal

    const uint4* gz = (const uint4*)zb;

    // prologue: stage tile 0
    {
        int jb = jb0;
        uint4 s0 = gz[jb * 32 + tid];
        uint4 s1 = gz[jb * 32 + 256 + tid];
        int lo0 = tid * 16;        int r0 = lo0 >> 9; int ph0 = lo0 ^ ((r0 & 7) << 4);
        int lo1 = 4096 + tid * 16; int r1 = lo1 >> 9; int ph1 = lo1 ^ ((r1 & 7) << 4);
        *(uint4*)(&lds[0][ph0]) = s0;
        *(uint4*)(&lds[0][ph1]) = s1;
    }
    __syncthreads();

    int cur = 0;
    for (int t = 0; t < JTILES; ++t) {
        const int jb = jb0 + t * 16;
        uint4 n0, n1;
        const bool more = (t + 1 < JTILES);
        if (more) {                       // issue next-tile loads early (T14)
            int jn = jb + 16;
            n0 = gz[jn * 32 + tid];
            n1 = gz[jn * 32 + 256 + tid];
        }

        // A fragments (j side) from swizzled LDS
        bf16x8 af[8];
        const char* base = lds[cur];
        #pragma unroll
        for (int kk = 0; kk < 8; ++kk) {
            int inrow = (kk << 6) | (kg << 4);
            af[kk] = *(const bf16x8*)(base + rbase + (inrow ^ swz));
        }

        #pragma unroll
        for (int is = 0; is < 4; ++is) {
            f32x4 acc = {0.f, 0.f, 0.f, 0.f};
            #pragma unroll
            for (int kk = 0; kk < 8; ++kk)
                acc = __builtin_amdgcn_mfma_f32_16x16x32_bf16(af[kk], bf[is][kk], acc, 0, 0, 0);

            if (jb == iw + is * 16) {     // diagonal tile: mask i==j
                #pragma unroll
                for (int r = 0; r < 4; ++r)
                    if (dr == r) acc[r] = -1e30f;
            }
            // online LSE update (natural domain, sim = 2*dot)
            float t0 = fmaxf(fmaxf(acc[0], acc[1]), fmaxf(acc[2], acc[3]));
            float mn = fmaxf(m[is], t0 * 2.0f);
            float s  = __expf(fmaf(acc[0], 2.0f, -mn)) + __expf(fmaf(acc[1], 2.0f, -mn))
                     + __expf(fmaf(acc[2], 2.0f, -mn)) + __expf(fmaf(acc[3], 2.0f, -mn));
            l[is] = l[is] * __expf(m[is] - mn) + s;
            m[is] = mn;
        }

        if (more) {                       // write next tile after this tile's reads
            char* dstb = lds[cur ^ 1];
            int lo0 = tid * 16;        int r0 = lo0 >> 9; int ph0 = lo0 ^ ((r0 & 7) << 4);
            int lo1 = 4096 + tid * 16; int r1 = lo1 >> 9; int ph1 = lo1 ^ ((r1 & 7) << 4);
            *(uint4*)(dstb + ph0) = n0;
            *(uint4*)(dstb + ph1) = n1;
        }
        __syncthreads();
        cur ^= 1;
    }

    // combine the 4 lanes (kg groups) holding the same i
    #pragma unroll
    for (int is = 0; is < 4; ++is) {
        float mm = m[is], ll = l[is];
        #pragma unroll
        for (int msk = 16; msk <= 32; msk <<= 1) {
            float mo  = __shfl_xor(mm, msk);
            float lo_ = __shfl_xor(ll, msk);
            float mn  = fmaxf(mm, mo);
            ll = ll * __expf(mm - mn) + lo_ * __expf(mo - mn);
            mm = mn;
        }
        if (kg == 0) {
            int i = iw + is * 16 + col;
            part[i * JS + js] = make_float2(mm, ll);
        }
    }
}

// ---------------- final: merge partials, loss, reduce ----------------
__global__ void k_final(const float2* __restrict__ part, const float* __restrict__ pos,
                        float* __restrict__ out) {
    int tid = threadIdx.x;
    int i = blockIdx.x * 256 + tid;
    const float2* p = part + (size_t)i * JS;
    float2 v[JS];
    float M = -3e30f;
    #pragma unroll
    for (int s = 0; s < JS; ++s) { v[s] = p[s]; M = fmaxf(M, v[s].x); }
    float L = 0.0f;
    #pragma unroll
    for (int s = 0; s < JS; ++s) L += v[s].y * __expf(v[s].x - M);
    float loss = M + __logf(L) - pos[i & (HALF - 1)];

    #pragma unroll
    for (int k = 32; k; k >>= 1) loss += __shfl_down(loss, k);
    __shared__ float ps[4];
    int w = tid >> 6, lane = tid & 63;
    if (lane == 0) ps[w] = loss;
    __syncthreads();
    if (tid == 0) atomicAdd(out, (ps[0] + ps[1] + ps[2] + ps[3]) * (1.0f / (float)NROWS));
}

extern "C" void kernel_launch(void* const* d_in, const int* in_sizes, int n_in,
                              void* d_out, int out_size, void* d_ws, size_t ws_size,
                              hipStream_t stream) {
    const float* z1 = (const float*)d_in[0];
    const float* z2 = (const float*)d_in[1];
    float* out = (float*)d_out;

    char* ws = (char*)d_ws;
    unsigned short* zb = (unsigned short*)ws;                          // 4 MiB
    float* pos  = (float*)(ws + 4u * 1024u * 1024u);                   // 16 KiB
    float2* part = (float2*)(ws + 4u * 1024u * 1024u + 65536u);        // 1 MiB

    hipMemsetAsync(d_out, 0, sizeof(float), stream);
    k_conv <<<1024, 256, 0, stream>>>(z1, z2, zb);
    k_pos  <<<1024, 256, 0, stream>>>(z1, z2, pos);
    k_main <<<512,  256, 0, stream>>>(zb, part);
    k_final<<<32,   256, 0, stream>>>(part, pos, out);
}

// Round 3
// 109.040 us; speedup vs baseline: 1.0192x; 1.0192x over previous
//
#include <hip/hip_runtime.h>

#define NROWS 8192
#define HALF  4096
#define DIM   256
#define JS    16                 // j-splits across grid
#define JRANGE (NROWS / JS)      // 512 columns per block
#define JTILES (JRANGE / 16)     // 32 tiles of 16 j each
#define IPB   256                // i rows per block
#define IPW   64                 // i rows per wave

typedef short bf16x8 __attribute__((ext_vector_type(8)));
typedef float f32x4  __attribute__((ext_vector_type(4)));

__device__ __forceinline__ unsigned short f2bf(float f) {
    unsigned int u = __float_as_uint(f);
    u += 0x7FFFu + ((u >> 16) & 1u);          // round-to-nearest-even
    return (unsigned short)(u >> 16);
}

// ------- fused prep: fp32 -> bf16 for both halves + exact fp32 positive dots -------
__global__ void k_prep(const float* __restrict__ z1, const float* __restrict__ z2,
                       unsigned short* __restrict__ zb, float* __restrict__ pos) {
    int w = threadIdx.x >> 6, lane = threadIdx.x & 63;
    int row = blockIdx.x * 4 + w;                    // 0 .. 4095
    float4 a = *(const float4*)(z1 + (size_t)row * DIM + lane * 4);
    float4 b = *(const float4*)(z2 + (size_t)row * DIM + lane * 4);

    uint2 pa, pb;
    pa.x = (unsigned int)f2bf(a.x) | ((unsigned int)f2bf(a.y) << 16);
    pa.y = (unsigned int)f2bf(a.z) | ((unsigned int)f2bf(a.w) << 16);
    pb.x = (unsigned int)f2bf(b.x) | ((unsigned int)f2bf(b.y) << 16);
    pb.y = (unsigned int)f2bf(b.z) | ((unsigned int)f2bf(b.w) << 16);
    *(uint2*)(zb + (size_t)row * DIM + lane * 4)          = pa;
    *(uint2*)(zb + (size_t)(row + HALF) * DIM + lane * 4) = pb;

    float d = a.x * b.x + a.y * b.y + a.z * b.z + a.w * b.w;
    #pragma unroll
    for (int k = 32; k; k >>= 1) d += __shfl_xor(d, k);
    if (lane == 0) pos[row] = 2.0f * d;              // sim units (1/T = 2)
}

// ---------------- main: MFMA matmul + online LSE ----------------
__global__ __launch_bounds__(256, 2)
void k_main(const unsigned short* __restrict__ zb, float2* __restrict__ part) {
    __shared__ __align__(16) char lds[2][8192];      // 2 x (16 j-rows x 512B)

    const int tid  = threadIdx.x;
    const int w    = tid >> 6;
    const int lane = tid & 63;
    const int col  = lane & 15;        // i-local (C column)
    const int kg   = lane >> 4;        // k-group / j-subrow group
    const int ib   = blockIdx.x & 31;  // 32 i-tiles
    const int js   = blockIdx.x >> 5;  // 16 j-splits
    const int iw   = ib * IPB + w * IPW;
    const int jb0  = js * JRANGE;

    // preload B fragments (i side): 4 subtiles x 8 k-steps, bf16x8 each
    bf16x8 bf[4][8];
    #pragma unroll
    for (int is = 0; is < 4; ++is) {
        const char* rowp = (const char*)zb + (size_t)(iw + is * 16 + col) * 512;
        #pragma unroll
        for (int kk = 0; kk < 8; ++kk)
            bf[is][kk] = *(const bf16x8*)(rowp + kk * 64 + kg * 16);
    }
    // Force register residency: opaque asm makes each fragment's value originate
    // here, so the compiler cannot rematerialize the global loads inside the
    // j-tile loop (round-2 counters: VGPR_Count=104 proved bf[] was NOT resident).
    #pragma unroll
    for (int is = 0; is < 4; ++is)
        #pragma unroll
        for (int kk = 0; kk < 8; ++kk)
            asm volatile("" : "+v"(bf[is][kk]));

    float m[4], l[4];
    #pragma unroll
    for (int is = 0; is < 4; ++is) { m[is] = -1e30f; l[is] = 0.0f; }

    const int swz   = (lane & 7) << 4;   // XOR swizzle key: (row&7)<<4, row = col
    const int rbase = col * 512;
    const int dr    = col - kg * 4;      // which acc reg hits the diagonal

    const uint4* gz = (const uint4*)zb;

    // prologue: stage tile 0
    {
        int jb = jb0;
        uint4 s0 = gz[jb * 32 + tid];
        uint4 s1 = gz[jb * 32 + 256 + tid];
        int lo0 = tid * 16;        int r0 = lo0 >> 9; int ph0 = lo0 ^ ((r0 & 7) << 4);
        int lo1 = 4096 + tid * 16; int r1 = lo1 >> 9; int ph1 = lo1 ^ ((r1 & 7) << 4);
        *(uint4*)(&lds[0][ph0]) = s0;
        *(uint4*)(&lds[0][ph1]) = s1;
    }
    __syncthreads();

    int cur = 0;
    for (int t = 0; t < JTILES; ++t) {
        const int jb = jb0 + t * 16;
        uint4 n0, n1;
        const bool more = (t + 1 < JTILES);
        if (more) {                       // issue next-tile loads early (T14)
            int jn = jb + 16;
            n0 = gz[jn * 32 + tid];
            n1 = gz[jn * 32 + 256 + tid];
        }

        // A fragments (j side) from swizzled LDS
        bf16x8 af[8];
        const char* base = lds[cur];
        #pragma unroll
        for (int kk = 0; kk < 8; ++kk) {
            int inrow = (kk << 6) | (kg << 4);
            af[kk] = *(const bf16x8*)(base + rbase + (inrow ^ swz));
        }

        #pragma unroll
        for (int is = 0; is < 4; ++is) {
            f32x4 acc = {0.f, 0.f, 0.f, 0.f};
            #pragma unroll
            for (int kk = 0; kk < 8; ++kk)
                acc = __builtin_amdgcn_mfma_f32_16x16x32_bf16(af[kk], bf[is][kk], acc, 0, 0, 0);

            if (jb == iw + is * 16) {     // diagonal tile: mask i==j
                #pragma unroll
                for (int r = 0; r < 4; ++r)
                    if (dr == r) acc[r] = -1e30f;
            }
            // online LSE update (natural domain, sim = 2*dot)
            float t0 = fmaxf(fmaxf(acc[0], acc[1]), fmaxf(acc[2], acc[3]));
            float mn = fmaxf(m[is], t0 * 2.0f);
            float s  = __expf(fmaf(acc[0], 2.0f, -mn)) + __expf(fmaf(acc[1], 2.0f, -mn))
                     + __expf(fmaf(acc[2], 2.0f, -mn)) + __expf(fmaf(acc[3], 2.0f, -mn));
            l[is] = l[is] * __expf(m[is] - mn) + s;
            m[is] = mn;
        }

        if (more) {                       // write next tile after this tile's reads
            char* dstb = lds[cur ^ 1];
            int lo0 = tid * 16;        int r0 = lo0 >> 9; int ph0 = lo0 ^ ((r0 & 7) << 4);
            int lo1 = 4096 + tid * 16; int r1 = lo1 >> 9; int ph1 = lo1 ^ ((r1 & 7) << 4);
            *(uint4*)(dstb + ph0) = n0;
            *(uint4*)(dstb + ph1) = n1;
        }
        __syncthreads();
        cur ^= 1;
    }

    // combine the 4 lanes (kg groups) holding the same i
    #pragma unroll
    for (int is = 0; is < 4; ++is) {
        float mm = m[is], ll = l[is];
        #pragma unroll
        for (int msk = 16; msk <= 32; msk <<= 1) {
            float mo  = __shfl_xor(mm, msk);
            float lo_ = __shfl_xor(ll, msk);
            float mn  = fmaxf(mm, mo);
            ll = ll * __expf(mm - mn) + lo_ * __expf(mo - mn);
            mm = mn;
        }
        if (kg == 0) {
            int i = iw + is * 16 + col;
            part[i * JS + js] = make_float2(mm, ll);
        }
    }
}

// ---------------- final: merge partials, loss, reduce ----------------
__global__ void k_final(const float2* __restrict__ part, const float* __restrict__ pos,
                        float* __restrict__ out) {
    int tid = threadIdx.x;
    int i = blockIdx.x * 256 + tid;
    const float2* p = part + (size_t)i * JS;
    float2 v[JS];
    float M = -3e30f;
    #pragma unroll
    for (int s = 0; s < JS; ++s) { v[s] = p[s]; M = fmaxf(M, v[s].x); }
    float L = 0.0f;
    #pragma unroll
    for (int s = 0; s < JS; ++s) L += v[s].y * __expf(v[s].x - M);
    float loss = M + __logf(L) - pos[i & (HALF - 1)];

    #pragma unroll
    for (int k = 32; k; k >>= 1) loss += __shfl_down(loss, k);
    __shared__ float ps[4];
    int w = tid >> 6, lane = tid & 63;
    if (lane == 0) ps[w] = loss;
    __syncthreads();
    if (tid == 0) atomicAdd(out, (ps[0] + ps[1] + ps[2] + ps[3]) * (1.0f / (float)NROWS));
}

extern "C" void kernel_launch(void* const* d_in, const int* in_sizes, int n_in,
                              void* d_out, int out_size, void* d_ws, size_t ws_size,
                              hipStream_t stream) {
    const float* z1 = (const float*)d_in[0];
    const float* z2 = (const float*)d_in[1];
    float* out = (float*)d_out;

    char* ws = (char*)d_ws;
    unsigned short* zb = (unsigned short*)ws;                          // 4 MiB
    float* pos  = (float*)(ws + 4u * 1024u * 1024u);                   // 16 KiB
    float2* part = (float2*)(ws + 4u * 1024u * 1024u + 65536u);        // 1 MiB

    hipMemsetAsync(d_out, 0, sizeof(float), stream);
    k_prep <<<1024, 256, 0, stream>>>(z1, z2, zb, pos);
    k_main <<<512,  256, 0, stream>>>(zb, part);
    k_final<<<32,   256, 0, stream>>>(part, pos, out);
}

// Round 5
// 106.438 us; speedup vs baseline: 1.0441x; 1.0244x over previous
//
#include <hip/hip_runtime.h>

#define NROWS 8192
#define HALF  4096
#define DIM   256
#define JS    16                 // j-splits across grid
#define JRANGE (NROWS / JS)      // 512 columns per block
#define JTILES (JRANGE / 16)     // 32 tiles of 16 j each
#define IPB   256                // i rows per block
#define IPW   64                 // i rows per wave

typedef short bf16x8 __attribute__((ext_vector_type(8)));
typedef float f32x4  __attribute__((ext_vector_type(4)));

__device__ __forceinline__ unsigned short f2bf(float f) {
    unsigned int u = __float_as_uint(f);
    u += 0x7FFFu + ((u >> 16) & 1u);          // round-to-nearest-even
    return (unsigned short)(u >> 16);
}

// --- fused prep: fp32 -> bf16 both halves + exact fp32 positive dots + out=0 ---
__global__ void k_prep(const float* __restrict__ z1, const float* __restrict__ z2,
                       unsigned short* __restrict__ zb, float* __restrict__ pos,
                       float* __restrict__ out) {
    if (blockIdx.x == 0 && threadIdx.x == 0) *out = 0.0f;   // replaces memset node
    int w = threadIdx.x >> 6, lane = threadIdx.x & 63;
    int row = blockIdx.x * 4 + w;                    // 0 .. 4095
    float4 a = *(const float4*)(z1 + (size_t)row * DIM + lane * 4);
    float4 b = *(const float4*)(z2 + (size_t)row * DIM + lane * 4);

    uint2 pa, pb;
    pa.x = (unsigned int)f2bf(a.x) | ((unsigned int)f2bf(a.y) << 16);
    pa.y = (unsigned int)f2bf(a.z) | ((unsigned int)f2bf(a.w) << 16);
    pb.x = (unsigned int)f2bf(b.x) | ((unsigned int)f2bf(b.y) << 16);
    pb.y = (unsigned int)f2bf(b.z) | ((unsigned int)f2bf(b.w) << 16);
    *(uint2*)(zb + (size_t)row * DIM + lane * 4)          = pa;
    *(uint2*)(zb + (size_t)(row + HALF) * DIM + lane * 4) = pb;

    float d = a.x * b.x + a.y * b.y + a.z * b.z + a.w * b.w;
    #pragma unroll
    for (int k = 32; k; k >>= 1) d += __shfl_xor(d, k);
    if (lane == 0) pos[row] = 2.0f * d;              // sim units (1/T = 2)
}

// ---------------- main: MFMA matmul + online LSE ----------------
__global__ __launch_bounds__(256, 2)
void k_main(const unsigned short* __restrict__ zb, float2* __restrict__ part) {
    __shared__ __align__(16) char lds[2][8192];      // 2 x (16 rows x 512B)
    char* ldsflat = &lds[0][0];

    const int tid  = threadIdx.x;
    const int w    = tid >> 6;
    const int lane = tid & 63;
    const int col  = lane & 15;        // i-local (C column)
    const int kg   = lane >> 4;        // k-group / j-subrow group
    const int ib   = blockIdx.x & 31;  // 32 i-tiles
    const int js   = blockIdx.x >> 5;  // 16 j-splits
    const int iw   = ib * IPB + w * IPW;
    const int jb0  = js * JRANGE;
    const int swz  = (lane & 7) << 4;  // XOR swizzle key ((row&7)<<4), row = col

    const uint4* gz = (const uint4*)zb;

    // ---- i-panel prologue: global -> LDS -> registers.  bf[] originates from
    // ds_read of a buffer that is ds_written inside the j-loop, so the compiler
    // CANNOT rematerialize these loads (round-2/3: VGPR=104 proved invariant
    // global loads were being re-fetched every tile -> L1-throughput-bound).
    bf16x8 bf[4][8];
    #pragma unroll
    for (int p = 0; p < 8; ++p) {                    // pass p: block rows [32p,32p+32)
        size_t gbase = (size_t)(ib * IPB + p * 32) * 32;   // uint4 units (32/row)
        #pragma unroll
        for (int k = 0; k < 4; ++k) {
            int e  = tid + k * 256;                  // 0..1023 (16KB / 16B)
            uint4 v = gz[gbase + e];
            int lo = e * 16;
            int r  = lo >> 9;                        // row within pass (0..31)
            *(uint4*)(ldsflat + (lo ^ ((r & 7) << 4))) = v;
        }
        __syncthreads();
        if ((p >> 1) == w) {                         // wave w owns passes 2w, 2w+1
            #pragma unroll
            for (int h = 0; h < 2; ++h) {            // tile h of this pass
                const char* tb = ldsflat + h * 8192;
                #pragma unroll
                for (int kk = 0; kk < 8; ++kk)
                    bf[(p & 1) * 2 + h][kk] =
                        *(const bf16x8*)(tb + col * 512 + (((kk << 6) | (kg << 4)) ^ swz));
            }
        }
        __syncthreads();
    }

    float m[4], l[4];
    #pragma unroll
    for (int is = 0; is < 4; ++is) { m[is] = -1e30f; l[is] = 0.0f; }

    const int rbase = col * 512;
    const int dr    = col - kg * 4;      // which acc reg hits the diagonal

    // prologue: stage j-tile 0
    {
        int jb = jb0;
        uint4 s0 = gz[jb * 32 + tid];
        uint4 s1 = gz[jb * 32 + 256 + tid];
        int lo0 = tid * 16;        int r0 = lo0 >> 9; int ph0 = lo0 ^ ((r0 & 7) << 4);
        int lo1 = 4096 + tid * 16; int r1 = lo1 >> 9; int ph1 = lo1 ^ ((r1 & 7) << 4);
        *(uint4*)(ldsflat + ph0) = s0;
        *(uint4*)(ldsflat + ph1) = s1;
    }
    __syncthreads();

    int cur = 0;
    for (int t = 0; t < JTILES; ++t) {
        const int jb = jb0 + t * 16;
        uint4 n0, n1;
        const bool more = (t + 1 < JTILES);
        if (more) {                       // issue next-tile loads early (T14)
            int jn = jb + 16;
            n0 = gz[jn * 32 + tid];
            n1 = gz[jn * 32 + 256 + tid];
        }

        // A fragments (j side) from swizzled LDS
        bf16x8 af[8];
        const char* base = lds[cur];
        #pragma unroll
        for (int kk = 0; kk < 8; ++kk) {
            int inrow = (kk << 6) | (kg << 4);
            af[kk] = *(const bf16x8*)(base + rbase + (inrow ^ swz));
        }

        #pragma unroll
        for (int is = 0; is < 4; ++is) {
            f32x4 acc = {0.f, 0.f, 0.f, 0.f};
            #pragma unroll
            for (int kk = 0; kk < 8; ++kk)
                acc = __builtin_amdgcn_mfma_f32_16x16x32_bf16(af[kk], bf[is][kk], acc, 0, 0, 0);

            if (jb == iw + is * 16) {     // diagonal tile: mask i==j
                #pragma unroll
                for (int r = 0; r < 4; ++r)
                    if (dr == r) acc[r] = -1e30f;
            }
            // online LSE update (natural domain, sim = 2*dot)
            float t0 = fmaxf(fmaxf(acc[0], acc[1]), fmaxf(acc[2], acc[3]));
            float mn = fmaxf(m[is], t0 * 2.0f);
            float s  = __expf(fmaf(acc[0], 2.0f, -mn)) + __expf(fmaf(acc[1], 2.0f, -mn))
                     + __expf(fmaf(acc[2], 2.0f, -mn)) + __expf(fmaf(acc[3], 2.0f, -mn));
            l[is] = l[is] * __expf(m[is] - mn) + s;
            m[is] = mn;
        }

        if (more) {                       // write next tile after this tile's reads
            char* dstb = lds[cur ^ 1];
            int lo0 = tid * 16;        int r0 = lo0 >> 9; int ph0 = lo0 ^ ((r0 & 7) << 4);
            int lo1 = 4096 + tid * 16; int r1 = lo1 >> 9; int ph1 = lo1 ^ ((r1 & 7) << 4);
            *(uint4*)(dstb + ph0) = n0;
            *(uint4*)(dstb + ph1) = n1;
        }
        __syncthreads();
        cur ^= 1;
    }

    // combine the 4 lanes (kg groups) holding the same i
    #pragma unroll
    for (int is = 0; is < 4; ++is) {
        float mm = m[is], ll = l[is];
        #pragma unroll
        for (int msk = 16; msk <= 32; msk <<= 1) {
            float mo  = __shfl_xor(mm, msk);
            float lo_ = __shfl_xor(ll, msk);
            float mn  = fmaxf(mm, mo);
            ll = ll * __expf(mm - mn) + lo_ * __expf(mo - mn);
            mm = mn;
        }
        if (kg == 0) {
            int i = iw + is * 16 + col;
            part[i * JS + js] = make_float2(mm, ll);
        }
    }
}

// ---------------- final: merge partials, loss, reduce ----------------
__global__ void k_final(const float2* __restrict__ part, const float* __restrict__ pos,
                        float* __restrict__ out) {
    int tid = threadIdx.x;
    int i = blockIdx.x * 256 + tid;
    const float2* p = part + (size_t)i * JS;
    float2 v[JS];
    float M = -3e30f;
    #pragma unroll
    for (int s = 0; s < JS; ++s) { v[s] = p[s]; M = fmaxf(M, v[s].x); }
    float L = 0.0f;
    #pragma unroll
    for (int s = 0; s < JS; ++s) L += v[s].y * __expf(v[s].x - M);
    float loss = M + __logf(L) - pos[i & (HALF - 1)];

    #pragma unroll
    for (int k = 32; k; k >>= 1) loss += __shfl_down(loss, k);
    __shared__ float ps[4];
    int w = tid >> 6, lane = tid & 63;
    if (lane == 0) ps[w] = loss;
    __syncthreads();
    if (tid == 0) atomicAdd(out, (ps[0] + ps[1] + ps[2] + ps[3]) * (1.0f / (float)NROWS));
}

extern "C" void kernel_launch(void* const* d_in, const int* in_sizes, int n_in,
                              void* d_out, int out_size, void* d_ws, size_t ws_size,
                              hipStream_t stream) {
    const float* z1 = (const float*)d_in[0];
    const float* z2 = (const float*)d_in[1];
    float* out = (float*)d_out;

    char* ws = (char*)d_ws;
    unsigned short* zb = (unsigned short*)ws;                          // 4 MiB
    float* pos  = (float*)(ws + 4u * 1024u * 1024u);                   // 16 KiB
    float2* part = (float2*)(ws + 4u * 1024u * 1024u + 65536u);        // 1 MiB

    k_prep <<<1024, 256, 0, stream>>>(z1, z2, zb, pos, out);
    k_main <<<512,  256, 0, stream>>>(zb, part);
    k_final<<<32,   256, 0, stream>>>(part, pos, out);
}

// Round 6
// 101.839 us; speedup vs baseline: 1.0912x; 1.0452x over previous
//
#include <hip/hip_runtime.h>

#define NROWS 8192
#define HALF  4096
#define DIM   256
#define JS    16                 // j-splits across grid
#define JRANGE 512               // columns per block
#define JTILES 32                // 16-row j-tiles per block
#define IPB   256                // i rows per block
#define IPW   64                 // i rows per wave

typedef short bf16x8 __attribute__((ext_vector_type(8)));
typedef float f32x4  __attribute__((ext_vector_type(4)));

// async global->LDS, 16B per lane; LDS dest = wave-uniform base + lane*16
#define GLOAD16(g, l) __builtin_amdgcn_global_load_lds( \
    (const __attribute__((address_space(1))) unsigned int*)(g), \
    (__attribute__((address_space(3))) unsigned int*)(l), 16, 0, 0)

__device__ __forceinline__ unsigned short f2bf(float f) {
    unsigned int u = __float_as_uint(f);
    u += 0x7FFFu + ((u >> 16) & 1u);          // round-to-nearest-even
    return (unsigned short)(u >> 16);
}

// --- prep: zb = bf16(sqrt(2)*z) (MFMA then yields sim units directly),
//     exact fp32 positive dots, out=0 ---
__global__ void k_prep(const float* __restrict__ z1, const float* __restrict__ z2,
                       unsigned short* __restrict__ zb, float* __restrict__ pos,
                       float* __restrict__ out) {
    if (blockIdx.x == 0 && threadIdx.x == 0) *out = 0.0f;
    const float R2 = 1.41421356237309515f;     // sqrt(2): (R2*z)·(R2*z) = 2*z·z = sim
    int w = threadIdx.x >> 6, lane = threadIdx.x & 63;
    int row = blockIdx.x * 4 + w;              // 0 .. 4095
    float4 a = *(const float4*)(z1 + (size_t)row * DIM + lane * 4);
    float4 b = *(const float4*)(z2 + (size_t)row * DIM + lane * 4);

    uint2 pa, pb;
    pa.x = (unsigned int)f2bf(a.x*R2) | ((unsigned int)f2bf(a.y*R2) << 16);
    pa.y = (unsigned int)f2bf(a.z*R2) | ((unsigned int)f2bf(a.w*R2) << 16);
    pb.x = (unsigned int)f2bf(b.x*R2) | ((unsigned int)f2bf(b.y*R2) << 16);
    pb.y = (unsigned int)f2bf(b.z*R2) | ((unsigned int)f2bf(b.w*R2) << 16);
    *(uint2*)(zb + (size_t)row * DIM + lane * 4)          = pa;
    *(uint2*)(zb + (size_t)(row + HALF) * DIM + lane * 4) = pb;

    float d = a.x * b.x + a.y * b.y + a.z * b.z + a.w * b.w;
    #pragma unroll
    for (int k = 32; k; k >>= 1) d += __shfl_xor(d, k);
    if (lane == 0) pos[row] = 2.0f * d;        // exact fp32, sim units
}

// ---------------- main: MFMA matmul + online LSE ----------------
__global__ __launch_bounds__(256, 2)
void k_main(const unsigned short* __restrict__ zb, float2* __restrict__ part) {
    __shared__ __align__(16) char lds[4][8192];  // 4 static 16-row buffers
    char* ldsflat = &lds[0][0];

    const int tid  = threadIdx.x;
    const int w    = tid >> 6;
    const int lane = tid & 63;
    const int col  = lane & 15;        // i-local (C column)
    const int kg   = lane >> 4;        // k-group / j-subrow group
    const int ib   = blockIdx.x & 31;  // 32 i-tiles
    const int js   = blockIdx.x >> 5;  // 16 j-splits
    const int iw   = ib * IPB + w * IPW;
    const int jb0  = js * JRANGE;
    const int swz  = (lane & 7) << 4;  // read-side XOR key ((row&7)<<4), row=col
    const int dr   = col - kg * 4;     // acc reg index hitting the diagonal

    const char* zbb = (const char*)zb;

    // pre-swizzled global source offsets (involution of the LDS XOR swizzle):
    // lds physical p gets data from logical p ^ ((p>>9 & 7)<<4)
    const int jp0 = w * 1024 + lane * 16;          // chunk 0 phys
    const int jp1 = 4096 + jp0;                    // chunk 1 phys
    const int jg0 = jp0 ^ (((jp0 >> 9) & 7) << 4);
    const int jg1 = jp1 ^ (((jp1 >> 9) & 7) << 4);

    // ---- i-panel prologue: global -> LDS (async, pre-swizzled) -> registers ----
    bf16x8 bf[4][8];
    {
        int igo[4];
        #pragma unroll
        for (int k = 0; k < 4; ++k) {
            int p = k * 4096 + w * 1024 + lane * 16;
            igo[k] = p ^ (((p >> 9) & 7) << 4);
        }
        #pragma unroll
        for (int p = 0; p < 8; ++p) {              // pass p: rows [32p, 32p+32)
            const char* gib = zbb + (size_t)(ib * IPB + p * 32) * 512;
            #pragma unroll
            for (int k = 0; k < 4; ++k)
                GLOAD16(gib + igo[k], ldsflat + k * 4096 + w * 1024);
            __syncthreads();                        // drains vmcnt -> data in LDS
            if ((p >> 1) == w) {                    // wave w owns passes 2w, 2w+1
                #pragma unroll
                for (int h = 0; h < 2; ++h) {
                    const char* tb = ldsflat + h * 8192;
                    #pragma unroll
                    for (int kk = 0; kk < 8; ++kk)
                        bf[(p & 1) * 2 + h][kk] =
                            *(const bf16x8*)(tb + col * 512 + (((kk << 6) | (kg << 4)) ^ swz));
                }
            }
            __syncthreads();
        }
    }

    float m[4], l[4];
    #pragma unroll
    for (int is = 0; is < 4; ++is) { m[is] = -1e30f; l[is] = 0.0f; }

    // static af addressing: one base + per-kk lane consts + buffer imm offsets
    const char* ap = ldsflat + col * 512;
    int aoff[8];
    #pragma unroll
    for (int kk = 0; kk < 8; ++kk) aoff[kk] = ((kk << 6) | (kg << 4)) ^ swz;

    const int dt = (iw - jb0) >> 4;                // tile idx of diagonal for is=0
    const char* jbase = zbb + (size_t)jb0 * 512;

#define JSTAGE(T, B) do { \
    GLOAD16(jbase + (size_t)(T) * 8192 + jg0, ldsflat + (B) * 8192 + w * 1024); \
    GLOAD16(jbase + (size_t)(T) * 8192 + jg1, ldsflat + (B) * 8192 + 4096 + w * 1024); \
} while (0)

#define COMPUTE_TILE(B, T) do { \
    bf16x8 af[8]; \
    _Pragma("unroll") \
    for (int kk = 0; kk < 8; ++kk) \
        af[kk] = *(const bf16x8*)(ap + aoff[kk] + (B) * 8192); \
    const int dd = (T) - dt; \
    _Pragma("unroll") \
    for (int is = 0; is < 4; ++is) { \
        f32x4 acc = {0.f, 0.f, 0.f, 0.f}; \
        _Pragma("unroll") \
        for (int kk = 0; kk < 8; ++kk) \
            acc = __builtin_amdgcn_mfma_f32_16x16x32_bf16(af[kk], bf[is][kk], acc, 0, 0, 0); \
        if (dd == is) { \
            _Pragma("unroll") \
            for (int r = 0; r < 4; ++r) if (dr == r) acc[r] = -1e30f; \
        } \
        float t0 = fmaxf(fmaxf(acc[0], acc[1]), fmaxf(acc[2], acc[3])); \
        if (__any(t0 > m[is])) {                 /* exact: factor is 1 when skipped */ \
            float mn = fmaxf(m[is], t0); \
            l[is] *= __expf(m[is] - mn); \
            m[is] = mn; \
        } \
        l[is] += __expf(acc[0] - m[is]) + __expf(acc[1] - m[is]) \
               + __expf(acc[2] - m[is]) + __expf(acc[3] - m[is]); \
    } \
} while (0)

    // prologue: tiles 0,1 -> L0,L1
    JSTAGE(0, 0); JSTAGE(1, 1);
    __syncthreads();

    for (int u = 0; u < 8; ++u) {
        const int t = u * 4;
        // half A: stage t+2,t+3 -> L2,L3 ; compute t (L0), t+1 (L1)
        JSTAGE(t + 2, 2); JSTAGE(t + 3, 3);
        COMPUTE_TILE(0, t);
        COMPUTE_TILE(1, t + 1);
        __syncthreads();
        // half B: stage t+4,t+5 -> L0,L1 ; compute t+2 (L2), t+3 (L3)
        if (u < 7) { JSTAGE(t + 4, 0); JSTAGE(t + 5, 1); }
        COMPUTE_TILE(2, t + 2);
        COMPUTE_TILE(3, t + 3);
        __syncthreads();
    }

    // combine the 4 kg groups holding the same i
    #pragma unroll
    for (int is = 0; is < 4; ++is) {
        float mm = m[is], ll = l[is];
        #pragma unroll
        for (int msk = 16; msk <= 32; msk <<= 1) {
            float mo  = __shfl_xor(mm, msk);
            float lo_ = __shfl_xor(ll, msk);
            float mn  = fmaxf(mm, mo);
            ll = ll * __expf(mm - mn) + lo_ * __expf(mo - mn);
            mm = mn;
        }
        if (kg == 0) {
            int i = iw + is * 16 + col;
            part[i * JS + js] = make_float2(mm, ll);
        }
    }
#undef JSTAGE
#undef COMPUTE_TILE
}

// ---------------- final: merge partials, loss, reduce ----------------
__global__ void k_final(const float2* __restrict__ part, const float* __restrict__ pos,
                        float* __restrict__ out) {
    int tid = threadIdx.x;
    int i = blockIdx.x * 256 + tid;
    const float2* p = part + (size_t)i * JS;
    float2 v[JS];
    float M = -3e30f;
    #pragma unroll
    for (int s = 0; s < JS; ++s) { v[s] = p[s]; M = fmaxf(M, v[s].x); }
    float L = 0.0f;
    #pragma unroll
    for (int s = 0; s < JS; ++s) L += v[s].y * __expf(v[s].x - M);
    float loss = M + __logf(L) - pos[i & (HALF - 1)];

    #pragma unroll
    for (int k = 32; k; k >>= 1) loss += __shfl_down(loss, k);
    __shared__ float ps[4];
    int w = tid >> 6, lane = tid & 63;
    if (lane == 0) ps[w] = loss;
    __syncthreads();
    if (tid == 0) atomicAdd(out, (ps[0] + ps[1] + ps[2] + ps[3]) * (1.0f / (float)NROWS));
}

extern "C" void kernel_launch(void* const* d_in, const int* in_sizes, int n_in,
                              void* d_out, int out_size, void* d_ws, size_t ws_size,
                              hipStream_t stream) {
    const float* z1 = (const float*)d_in[0];
    const float* z2 = (const float*)d_in[1];
    float* out = (float*)d_out;

    char* ws = (char*)d_ws;
    unsigned short* zb = (unsigned short*)ws;                          // 4 MiB
    float* pos  = (float*)(ws + 4u * 1024u * 1024u);                   // 16 KiB
    float2* part = (float2*)(ws + 4u * 1024u * 1024u + 65536u);        // 1 MiB

    k_prep <<<1024, 256, 0, stream>>>(z1, z2, zb, pos, out);
    k_main <<<512,  256, 0, stream>>>(zb, part);
    k_final<<<32,   256, 0, stream>>>(part, pos, out);
}